// Round 1
// baseline (820.400 us; speedup 1.0000x reference)
//
#include <hip/hip_runtime.h>
#include <hip/hip_bf16.h>

// Problem constants (from reference)
#define BB_ 1024      // batch
#define LL_ 100       // L
#define CC_ 1024      // C
#define UU_ 512       // U
#define WIN_ 3
#define NW_ 9         // WIN*WIN
#define GG_ 10        // G

// ---------------------------------------------------------------------------
// k_prep: per-batch p_t -> starts -> rowbase (9 gather row offsets per b).
// f64 accumulation to stay closer to the true value than the f32 reference's
// own rounding noise (int-truncation boundary safety).
// ---------------------------------------------------------------------------
__global__ __launch_bounds__(128) void k_prep(
    const float* __restrict__ hidden,   // [B,512]
    const float* __restrict__ Wa,       // [512,100]
    const float* __restrict__ Wb,       // [100,2]
    int* __restrict__ rowbase)          // [B*9] element offsets into features
{
    constexpr int NB = 8;               // batches per block
    const int b0 = blockIdx.x * NB;
    const int tid = threadIdx.x;
    __shared__ float hsh[NB][UU_];
    __shared__ float ash[NB][100];
    __shared__ int   st_sh[NB][2];

    // load 8 hidden rows (4096 floats) via float4
    const float4* hsrc = (const float4*)(hidden + (long)b0 * UU_);
    float4* hdst = (float4*)&hsh[0][0];
    for (int i = tid; i < NB * UU_ / 4; i += 128) hdst[i] = hsrc[i];
    __syncthreads();

    if (tid < 100) {
        double acc[NB];
#pragma unroll
        for (int bb = 0; bb < NB; ++bb) acc[bb] = 0.0;
        for (int c = 0; c < UU_; ++c) {
            float w = Wa[c * 100 + tid];
#pragma unroll
            for (int bb = 0; bb < NB; ++bb)
                acc[bb] += (double)hsh[bb][c] * (double)w;
        }
#pragma unroll
        for (int bb = 0; bb < NB; ++bb) ash[bb][tid] = (float)tanh(acc[bb]);
    }
    __syncthreads();

    if (tid < NB * 2) {
        int bb = tid >> 1, k = tid & 1;
        double z = 0.0;
        for (int j = 0; j < 100; ++j)
            z += (double)ash[bb][j] * (double)Wb[j * 2 + k];
        double p = 1.0 / (1.0 + exp(-z));
        float pt = (float)(p * 8.0 + 1.0);   // p_t*(sqrt(100)-2)+1
        int st = (int)(pt - 1.0f);           // truncate (>=0)
        st = st < 0 ? 0 : (st > GG_ - WIN_ ? GG_ - WIN_ : st);  // dynamic_slice clamp
        st_sh[bb][k] = st;
    }
    __syncthreads();

    if (tid < NB * NW_) {
        int bb = tid / NW_, j = tid % NW_;
        int jj = j / WIN_, kk = j % WIN_;
        int b = b0 + bb;
        int pos = (st_sh[bb][0] + jj) * GG_ + (st_sh[bb][1] + kk);
        rowbase[b * NW_ + j] = b * (LL_ * CC_) + pos * CC_;
    }
}

// ---------------------------------------------------------------------------
// Generic tiled f32 GEMM: C[M,N] = act( A[M,K] @ B[K,N] + bias + addv )
//   - rowbase != null: A row r starts at A + rowbase[r] (K contiguous)
//   - addv != null: add addv[(r/addDiv)*N + n] (per-batch broadcast)
//   - act == 1: tanh
// BN=64 fixed, 256 threads, thread tile TM x 4.
// ---------------------------------------------------------------------------
template<int BM, int TM>
__global__ __launch_bounds__(256) void gemm_f32(
    int M, int N, int K,
    const float* __restrict__ A, const int* __restrict__ rowbase, int lda,
    const float* __restrict__ Bm,
    const float* __restrict__ bias,
    const float* __restrict__ addv, int addDiv,
    int act,
    float* __restrict__ C)
{
    constexpr int BN = 64, BK = 16, TN = 4;
    __shared__ float As[BK][BM];
    __shared__ float Bs[BK][BN];
    const int tid = threadIdx.x;
    const int row0 = blockIdx.x * BM, col0 = blockIdx.y * BN;
    const int ty = tid / 16, tx = tid % 16;
    float acc[TM][TN];
#pragma unroll
    for (int i = 0; i < TM; ++i)
#pragma unroll
        for (int j = 0; j < TN; ++j) acc[i][j] = 0.f;

    constexpr int ALOAD = BM * BK / 4;          // float4s for the A tile
    const int arow = tid / (BK / 4);
    const int akq  = (tid % (BK / 4)) * 4;
    const float* Aptr = nullptr;
    if (tid < ALOAD) {
        long abase = rowbase ? (long)rowbase[row0 + arow]
                             : (long)(row0 + arow) * lda;
        Aptr = A + abase + akq;
    }
    const int bkr = tid / 16;                   // 0..15 (k within tile)
    const int bnq = (tid % 16) * 4;             // n within tile
    const float* Bptr = Bm + (long)bkr * N + col0 + bnq;

    for (int k0 = 0; k0 < K; k0 += BK) {
        float4 av = make_float4(0.f, 0.f, 0.f, 0.f);
        if (tid < ALOAD) av = *(const float4*)(Aptr + k0);
        float4 bv = *(const float4*)(Bptr + (long)k0 * N);
        __syncthreads();   // previous iter's LDS reads done
        if (tid < ALOAD) {
            As[akq + 0][arow] = av.x;
            As[akq + 1][arow] = av.y;
            As[akq + 2][arow] = av.z;
            As[akq + 3][arow] = av.w;
        }
        *(float4*)&Bs[bkr][bnq] = bv;
        __syncthreads();
#pragma unroll
        for (int k = 0; k < BK; ++k) {
            float a[TM], b[TN];
#pragma unroll
            for (int i = 0; i < TM; ++i) a[i] = As[k][ty * TM + i];
#pragma unroll
            for (int j = 0; j < TN; ++j) b[j] = Bs[k][tx * TN + j];
#pragma unroll
            for (int i = 0; i < TM; ++i)
#pragma unroll
                for (int j = 0; j < TN; ++j) acc[i][j] += a[i] * b[j];
        }
    }

#pragma unroll
    for (int i = 0; i < TM; ++i) {
        int r = row0 + ty * TM + i;
        int n0 = col0 + tx * TN;
        const float* addp = addv ? addv + (long)(r / addDiv) * N + n0 : nullptr;
        float vv[4];
#pragma unroll
        for (int j = 0; j < TN; ++j) {
            float x = acc[i][j];
            if (bias) x += bias[n0 + j];
            if (addp) x += addp[j];
            if (act == 1) x = tanhf(x);
            vv[j] = x;
        }
        *(float4*)(C + (long)r * N + n0) = *(float4*)vv;
    }
}

// ---------------------------------------------------------------------------
// k_attn_ctx: per-b (one block): logits = score@V1 + b, softmax*gauss -> attn
// (written to output), ctx = sum_j attn_j * local_j, t = tanh([ctx, hidden]).
// ---------------------------------------------------------------------------
__global__ __launch_bounds__(256) void k_attn_ctx(
    const float* __restrict__ score,     // [B*9*512] (already tanh'd)
    const float* __restrict__ features,  // [B*L*C]
    const int* __restrict__ rowbase,     // [B*9]
    const float* __restrict__ hidden,    // [B*512]
    const float* __restrict__ V1_w,      // [512]
    const float* __restrict__ V1_b,      // [1]
    float* __restrict__ t_out,           // [B*1536]
    float* __restrict__ attn_out)        // [B*9]
{
    const int b = blockIdx.x;
    const int tid = threadIdx.x;
    const int lane = tid & 63, wid = tid >> 6;
    __shared__ float red[4][NW_];
    __shared__ float attn_sh[NW_];
    __shared__ int rb_sh[NW_];

    const float* sb = score + (long)b * NW_ * UU_;
    float v1a = V1_w[tid];
    float v1b = V1_w[tid + 256];
    float part[NW_];
#pragma unroll
    for (int j = 0; j < NW_; ++j)
        part[j] = sb[j * UU_ + tid] * v1a + sb[j * UU_ + tid + 256] * v1b;
#pragma unroll
    for (int j = 0; j < NW_; ++j)
        for (int off = 32; off > 0; off >>= 1)
            part[j] += __shfl_down(part[j], off);
    if (lane == 0) {
#pragma unroll
        for (int j = 0; j < NW_; ++j) red[wid][j] = part[j];
    }
    if (tid < NW_) rb_sh[tid] = rowbase[b * NW_ + tid];
    __syncthreads();

    if (tid == 0) {
        float l[NW_], m = -1e30f;
#pragma unroll
        for (int j = 0; j < NW_; ++j) {
            l[j] = red[0][j] + red[1][j] + red[2][j] + red[3][j] + V1_b[0];
            m = fmaxf(m, l[j]);
        }
        float s = 0.f;
#pragma unroll
        for (int j = 0; j < NW_; ++j) { l[j] = expf(l[j] - m); s += l[j]; }
        float inv = 1.f / s;
#pragma unroll
        for (int j = 0; j < NW_; ++j) {
            int jj = j / WIN_, kk = j % WIN_;
            float dj = jj - 1.5f, dk = kk - 1.5f;
            float g = expf(-2.f * (dj * dj + dk * dk));  // exp(-d2/(0.5*D*D))
            float a = l[j] * inv * g;
            attn_sh[j] = a;
            attn_out[b * NW_ + j] = a;
        }
    }
    __syncthreads();

    float att[NW_];
#pragma unroll
    for (int j = 0; j < NW_; ++j) att[j] = attn_sh[j];

    for (int c = tid; c < CC_; c += 256) {
        float s = 0.f;
#pragma unroll
        for (int j = 0; j < NW_; ++j) s += att[j] * features[rb_sh[j] + c];
        t_out[(long)b * (CC_ + UU_) + c] = tanhf(s);
    }
    for (int u = tid; u < UU_; u += 256)
        t_out[(long)b * (CC_ + UU_) + CC_ + u] = tanhf(hidden[(long)b * UU_ + u]);
}

// ---------------------------------------------------------------------------
extern "C" void kernel_launch(void* const* d_in, const int* in_sizes, int n_in,
                              void* d_out, int out_size, void* d_ws, size_t ws_size,
                              hipStream_t stream) {
    const float* features = (const float*)d_in[0];
    const float* hidden   = (const float*)d_in[1];
    const float* W1_w = (const float*)d_in[2];
    const float* W1_b = (const float*)d_in[3];
    const float* W2_w = (const float*)d_in[4];
    const float* W2_b = (const float*)d_in[5];
    const float* V1_w = (const float*)d_in[6];
    const float* V1_b = (const float*)d_in[7];
    const float* W3_w = (const float*)d_in[8];
    const float* W3_b = (const float*)d_in[9];
    const float* Wa   = (const float*)d_in[10];
    const float* Wb   = (const float*)d_in[11];

    float* out_main = (float*)d_out;                       // [1024*512]
    float* out_attn = (float*)d_out + (long)BB_ * UU_;     // [1024*9]

    // workspace layout (256B aligned)
    char* ws = (char*)d_ws;
    int*   rowbase = (int*)ws;                                    // 36,864 B
    float* hW2     = (float*)(ws + 65536);                        // 2 MB
    float* scoreb  = (float*)(ws + 65536 + 2097152);              // 18.9 MB
    float* tbuf    = (float*)(ws + 65536 + 2097152 + 18874368);   // 6.3 MB

    // 1. starts + rowbase
    k_prep<<<BB_ / 8, 128, 0, stream>>>(hidden, Wa, Wb, rowbase);

    // 2. hW2 = hidden @ W2_w + W2_b          (1024 x 512 x 512)
    gemm_f32<32, 2><<<dim3(BB_ / 32, UU_ / 64), 256, 0, stream>>>(
        BB_, UU_, UU_, hidden, nullptr, UU_, W2_w, W2_b,
        nullptr, 1, 0, hW2);

    // 3. score = tanh(local @ W1_w + W1_b + hW2[b])   (9216 x 512 x 1024)
    gemm_f32<64, 4><<<dim3(BB_ * NW_ / 64, UU_ / 64), 256, 0, stream>>>(
        BB_ * NW_, UU_, CC_, features, rowbase, 0, W1_w, W1_b,
        hW2, NW_, 1, scoreb);

    // 4. logits/softmax*gauss -> attn out; ctx; t = tanh([ctx, hidden])
    k_attn_ctx<<<BB_, 256, 0, stream>>>(
        scoreb, features, rowbase, hidden, V1_w, V1_b, tbuf, out_attn);

    // 5. out = t @ W3_w + W3_b               (1024 x 512 x 1536)
    gemm_f32<32, 2><<<dim3(BB_ / 32, UU_ / 64), 256, 0, stream>>>(
        BB_, UU_, CC_ + UU_, tbuf, nullptr, CC_ + UU_, W3_w, W3_b,
        nullptr, 1, 0, out_main);
}